// Round 6
// baseline (1860.926 us; speedup 1.0000x reference)
//
#include <hip/hip_runtime.h>
#include <stdint.h>

typedef uint16_t u16;
typedef unsigned long long u64;
typedef __attribute__((ext_vector_type(8))) short short8;   // 8 x bf16 bits (4 VGPRs)
typedef __attribute__((ext_vector_type(4))) float f32x4;

#define SCOPE __HIP_MEMORY_SCOPE_AGENT
#define FSTRIDE 16   // ints per edge flag line (64B): 4 per-wave flags
#define FLD(p) __hip_atomic_load((p), __ATOMIC_RELAXED, SCOPE)
#define FST(p, v) __hip_atomic_store((p), (v), __ATOMIC_RELAXED, SCOPE)

template <int N> struct IC { static constexpr int value = N; };

static __device__ __forceinline__ float bf2f(u16 b) {
  union { uint32_t u; float f; } x; x.u = ((uint32_t)b) << 16; return x.f;
}
static __device__ __forceinline__ u16 f2bf(float f) {
  union { float f; uint32_t u; } x; x.f = f;
  uint32_t u = x.u;
  u += 0x7fffu + ((u >> 16) & 1u);   // RTNE
  return (u16)(u >> 16);
}
// inf-safe: exp(+inf)->inf, 1+inf=inf, rcp(inf)=0; exp(-inf)->0.
static __device__ __forceinline__ float sigm(float x) {
  return __builtin_amdgcn_rcpf(1.f + __expf(-x));
}
static __device__ __forceinline__ float tanhf_(float x) {
  return 1.f - 2.f * __builtin_amdgcn_rcpf(1.f + __expf(2.f * x));
}
// LDS-only barrier: does NOT drain vmcnt.
static __device__ __forceinline__ void lds_barrier() {
  asm volatile("s_waitcnt lgkmcnt(0)\n\ts_barrier" ::: "memory");
}
#define DRAIN0() asm volatile("s_waitcnt vmcnt(0)" ::: "memory")
static __device__ __forceinline__ int imin(int a, int b) { return a < b ? a : b; }

// R15: elasticity fix for the jitter-coupled handshake.
// Post-mortem R14: occupancy doubled (signature) but dur flat -> slot period
// (~3.3us vs ~1.1us of real pipe work) is invariant to local compute/occupancy
// => the residue is coupling dynamics: probes refreshed once/chunk with
// ~1-chunk staleness + tight credit windows keep the steady-state lag AT the
// blocking boundary, so chunk-starts keep taking the serial MALL-poll slow
// path and bubbles propagate (marching-band pipeline).
// Fixes: (1) probes issued EVERY slot, published next slot (staleness 1 slot);
// (2) big rings: enc+dec both in ws when it fits (R up to 256 -> no wrap ->
// credit direction OFF; else RC=R/CH-2 chunks slack); d_out borrow only as
// fallback; (3) Y posts chunk flag at slot tt==1 BEFORE doB so DRAIN0 covers
// only >=1-slot-old stores (no exposed write RTT); CH=4 where slack allows.
// MFMA 16x16x32 bf16 layouts (m89-verified):
//   A-frag: lane holds A[m=lane&15][k=(lane>>4)*8+j]
//   B-frag: lane holds B[k=(lane>>4)*8+j][n=lane&15]  (W row-major (N,K))
//   C/D: reg p -> (row=(lane>>4)*4+p, col=lane&15)
#define OFF_WHA 0
#define OFF_WHB 12288
#define OFF_WIB 24576
#define OFF_WIA 36864
#define OFF_WO  49152

template <int CHE, int CHD>
__global__ __launch_bounds__(512, 1) void gru_pipeline(
    const void* ctx_,
    const void* eWih0_, const void* eWih_, const void* eWhh_,
    const void* ebih_,  const void* ebhh_,
    const void* dWih0_, const void* dWih_, const void* dWhh_,
    const void* dbih_,  const void* dbhh_,
    const void* Wo_,    const void* bo_,   void* out_,
    int* __restrict__ pflag, int* __restrict__ cflag,
    u64* __restrict__ ringE, u64* __restrict__ ringD, int RE, int RW)
{
  const int tid  = threadIdx.x;
  const bool isX = (tid < 256);   // X: layer A of step t; Y: layer B of step t-1
  const int lane = tid & 63;
  const int qg   = (tid >> 6) & 3;  // wave within group
  const int w8   = tid >> 6;        // 0..7
  const int lo   = lane & 15;
  const int hi   = lane >> 4;
  const int blk  = blockIdx.x;
  const int P    = blk >> 3;      // layer pair 0..31
  const int g    = blk & 7;       // batch chunk (16 rows)
  const int LA   = 2 * P;
  const int NKCA = (P == 0) ? 4 : 2;

  extern __shared__ __align__(16) u16 dynlds[];   // weight tiles (120KB)

  __shared__ __align__(16) u16 hbA[2][16 * 72];
  __shared__ __align__(16) u16 hbB[2][16 * 72];
  __shared__ __align__(16) u16 xstA[2][16 * 72];
  __shared__ int s_cnt, s_fin, s_cn;
  if (tid == 0) { s_cnt = 0; s_fin = 0; s_cn = 0; }
  for (int i = tid; i < 16 * 72; i += 512) {
    hbA[0][i] = 0; hbA[1][i] = 0; hbB[0][i] = 0; hbB[1][i] = 0;
    xstA[0][i] = 0; xstA[1][i] = 0;
  }
  __syncthreads();
  {  // dtype probe: even u16s of enc_bih
    u16 v = ((const u16*)ebih_)[2 * (tid & 255)];
    int e = (v >> 7) & 0xFF;
    if (e >= 100 && e <= 126 && isX) atomicAdd(&s_cnt, 1);
  }
  __syncthreads();
  const bool bf = (s_cnt >= 128);   // true: bf16 tensors; false: fp32

  auto ld8 = [&](const void* p, int idx) -> short8 {
    if (bf) return *(const short8*)((const u16*)p + idx);
    const float* f = (const float*)p + idx;
    short8 r;
#pragma unroll
    for (int j = 0; j < 8; ++j) r[j] = (short)f2bf(f[j]);
    return r;
  };
  auto ld1 = [&](const void* p, int idx) -> float {
    return bf ? bf2f(((const u16*)p)[idx]) : ((const float*)p)[idx];
  };

  const int T0 = qg, T1 = 4 + qg, T2 = 8 + qg;

  short8 zf8 = {0,0,0,0,0,0,0,0};
  float  bov[2] = {0.f, 0.f};
  float brzA[2] = {0,0}, binA = 0, bhnA = 0;
  float brzB[2] = {0,0}, binB = 0, bhnB = 0;

  // ---- cooperative stage of a row-major (NT*16 x KC*32) matrix into LDS tiles
  auto stage_w = [&](int offU16, const void* W, int gidx0, int NT, int KC, int K) {
    for (int nt = w8; nt < NT; nt += 8)
      for (int kc = 0; kc < KC; ++kc) {
        short8 v = ld8(W, gidx0 + (nt*16 + lo)*K + kc*32 + hi*8);
        *(short8*)(dynlds + offU16 + (nt*KC + kc)*512 + lane*8) = v;
      }
  };

  auto load_phase = [&](int ph) {
    const void* WH  = ph ? dWhh_ : eWhh_;
    const void* WIs = ph ? dWih_ : eWih_;
    const void* WI0 = ph ? dWih0_ : eWih0_;
    const void* bi  = ph ? dbih_ : ebih_;
    const void* bh  = ph ? dbhh_ : ebhh_;
    stage_w(OFF_WHA, WH, LA*192*64, 12, 2, 64);
    stage_w(OFF_WHB, WH, (LA+1)*192*64, 12, 2, 64);
    stage_w(OFF_WIB, WIs, LA*192*64, 12, 2, 64);   // Wih[LB-1] = Wih[LA]
    if (LA == 0) stage_w(OFF_WIA, WI0, 0, 12, 4, 128);
    else         stage_w(OFF_WIA, WIs, (LA-1)*192*64, 12, 2, 64);
    if (isX) {
      brzA[0] = ld1(bi, LA*192 + T0*16 + lo) + ld1(bh, LA*192 + T0*16 + lo);
      brzA[1] = ld1(bi, LA*192 + T1*16 + lo) + ld1(bh, LA*192 + T1*16 + lo);
      binA    = ld1(bi, LA*192 + T2*16 + lo);
      bhnA    = ld1(bh, LA*192 + T2*16 + lo);
    } else {
      const int LB = LA + 1;
      brzB[0] = ld1(bi, LB*192 + T0*16 + lo) + ld1(bh, LB*192 + T0*16 + lo);
      brzB[1] = ld1(bi, LB*192 + T1*16 + lo) + ld1(bh, LB*192 + T1*16 + lo);
      binB    = ld1(bi, LB*192 + T2*16 + lo);
      bhnB    = ld1(bh, LB*192 + T2*16 + lo);
    }
  };
  load_phase(0);
  if (P == 31) {   // Wo staged once (OFF_WO untouched by load_phase(1): KCA=2)
    stage_w(OFF_WO, Wo_, 0, 8, 2, 64);
    if (!isX) { bov[0] = ld1(bo_, 32*qg + lo); bov[1] = ld1(bo_, 32*qg + 16 + lo); }
  }

  // ---- precomputed LDS u16 offsets for weight fragments
  const int oWhA0 = OFF_WHA + T0*1024 + lane*8;
  const int oWhA1 = OFF_WHA + T1*1024 + lane*8;
  const int oWhA2 = OFF_WHA + T2*1024 + lane*8;
  const int oWhB0 = OFF_WHB + T0*1024 + lane*8;
  const int oWhB1 = OFF_WHB + T1*1024 + lane*8;
  const int oWhB2 = OFF_WHB + T2*1024 + lane*8;
  const int oWiB0 = OFF_WIB + T0*1024 + lane*8;
  const int oWiB1 = OFF_WIB + T1*1024 + lane*8;
  const int oWiB2 = OFF_WIB + T2*1024 + lane*8;
  const int oWiA0 = OFF_WIA + T0*(NKCA*512) + lane*8;
  const int oWiA1 = OFF_WIA + T1*(NKCA*512) + lane*8;
  const int oWiA2 = OFF_WIA + T2*(NKCA*512) + lane*8;
  const int oWo0  = OFF_WO + (2*qg + 0)*1024 + lane*8;
  const int oWo1  = OFF_WO + (2*qg + 1)*1024 + lane*8;

  auto WF = [&](int off, int kc) -> short8 {   // one ds_read_b128, kc -> imm
    return *(const short8*)(dynlds + off + kc*512);
  };

  auto do_proj = [&](int tprev, const u16* hs) {   // Y-group only
    f32x4 pacc[2];
#pragma unroll
    for (int ct = 0; ct < 2; ++ct) { float v = bov[ct]; f32x4 tv = {v,v,v,v}; pacc[ct] = tv; }
#pragma unroll
    for (int kc = 0; kc < 2; ++kc) {
      short8 hA = *(const short8*)(hs + lo*72 + kc*32 + hi*8);
      pacc[0] = __builtin_amdgcn_mfma_f32_16x16x32_bf16(hA, WF(oWo0, kc), pacc[0], 0, 0, 0);
      pacc[1] = __builtin_amdgcn_mfma_f32_16x16x32_bf16(hA, WF(oWo1, kc), pacc[1], 0, 0, 0);
    }
#pragma unroll
    for (int ct = 0; ct < 2; ++ct) {
      int n = 32*qg + 16*ct + lo;
#pragma unroll
      for (int p = 0; p < 4; ++p) {
        int b = 16*g + hi*4 + p;
        size_t idx = ((size_t)b * 256 + (tprev - 256)) * 128 + n;
        float v = fminf(64.f, fmaxf(-64.f, pacc[ct][p]));
        if (bf) ((u16*)out_)[idx] = f2bf(v);
        else    ((float*)out_)[idx] = v;
      }
    }
  };

  float hprevA[4] = {0,0,0,0}, hprevB[4] = {0,0,0,0};
  const int brow = 16*g + lo;   // P0 context row

  const int eIn  = (P > 0 ? P - 1 : 0) * 8 + g;
  const int eOut = (P < 31 ? P : 30) * 8 + g;
  int* fin   = pflag + eIn  * FSTRIDE;
  int* fout  = pflag + eOut * FSTRIDE;
  int* cself = cflag + (P * 8 + g) * FSTRIDE;
  int* cnext = cflag + ((P < 31 ? P + 1 : 31) * 8 + g) * FSTRIDE;

  // ring address of record t (consumer side / producer side)
  auto raddr = [&](int t) -> const u64* {
    return (t < 256)
      ? (ringE + (size_t)eIn * ((size_t)RE * 256) + (size_t)(t & (RE-1)) * 256)
      : (ringD + (size_t)eIn * ((size_t)RW * 256) + (size_t)((t-256) & (RW-1)) * 256);
  };
  auto waddr = [&](int t) -> u64* {
    return (t < 256)
      ? (ringE + (size_t)eOut * ((size_t)RE * 256) + (size_t)(t & (RE-1)) * 256)
      : (ringD + (size_t)eOut * ((size_t)RW * 256) + (size_t)((t-256) & (RW-1)) * 256);
  };

  int budget = 1 << 22;   // anti-hang
  const int srow = 4 * (tid & 3);   // X record unpack: row quad
  const int scol = tid >> 2;        // X record unpack: h column (tid<256)

  int f0=0,f1=0,f2=0,f3=0, c0=0,c1=0,c2=0,c3=0;   // tid0 probe holds (1-slot stale)
  short8 cfx[4] = {zf8, zf8, zf8, zf8};           // P0 ctx prefetch (X)

  // ---- layer-B step (Y): compute B(s), write hbB[s&1], ring-store record(s)
  auto doB = [&](int s) {
    f32x4 br, bz, bin2, bhn;
    { float v;
      v = brzB[0]; br   = (f32x4){v,v,v,v};
      v = brzB[1]; bz   = (f32x4){v,v,v,v};
      v = binB;    bin2 = (f32x4){v,v,v,v};
      v = bhnB;    bhn  = (f32x4){v,v,v,v}; }
    const u16* hsB = hbB[(s + 1) & 1];   // h_B(s-1)
    const u16* xsB = hbA[s & 1];         // h_A(s)
#pragma unroll
    for (int kc = 0; kc < 2; ++kc) {
      short8 hB = *(const short8*)(hsB + lo*72 + kc*32 + hi*8);
      short8 xB = *(const short8*)(xsB + lo*72 + kc*32 + hi*8);
      br   = __builtin_amdgcn_mfma_f32_16x16x32_bf16(hB, WF(oWhB0, kc), br,   0, 0, 0);
      bz   = __builtin_amdgcn_mfma_f32_16x16x32_bf16(hB, WF(oWhB1, kc), bz,   0, 0, 0);
      bhn  = __builtin_amdgcn_mfma_f32_16x16x32_bf16(hB, WF(oWhB2, kc), bhn,  0, 0, 0);
      br   = __builtin_amdgcn_mfma_f32_16x16x32_bf16(xB, WF(oWiB0, kc), br,   0, 0, 0);
      bz   = __builtin_amdgcn_mfma_f32_16x16x32_bf16(xB, WF(oWiB1, kc), bz,   0, 0, 0);
      bin2 = __builtin_amdgcn_mfma_f32_16x16x32_bf16(xB, WF(oWiB2, kc), bin2, 0, 0, 0);
    }
    u16 hBb[4];
#pragma unroll
    for (int p = 0; p < 4; ++p) {
      float r = sigm(br[p]);
      float z = sigm(bz[p]);
      float n = tanhf_(bin2[p] + r * bhn[p]);
      float h = n + z * (hprevB[p] - n);
      h = fminf(1.f, fmaxf(-1.f, h));
      hprevB[p] = h;
      hBb[p] = f2bf(h);
    }
    u16* hd = hbB[s & 1];
#pragma unroll
    for (int p = 0; p < 4; ++p)
      hd[(hi*4 + p) * 72 + qg*16 + lo] = hBb[p];
    if (P < 31) {
      u64 da = (u64)hBb[0] | ((u64)hBb[1] << 16) | ((u64)hBb[2] << 32) | ((u64)hBb[3] << 48);
      FST(waddr(s) + (16*qg + lo)*4 + hi, da);
    }
  };

  __syncthreads();   // weight tiles + buffers visible

  // ---------------- span: slots t = tbase..tbase+255 (X:A(t), Y:B(t-1)) + tail
  auto span = [&](auto chc, const int tbase, const int cbase, const int RC, const bool dec) {
    constexpr int CH = decltype(chc)::value;
    const int NC = 256 / CH;
    const bool credOn = (RC < NC);

    // ---- prologue: wait + stage x(tbase); P0: ctx prefetch for tbase
    if (P > 0) {
      if (tid == 0) {
        int v = s_fin;
        if (v < cbase + 1) {
          while (budget > 0) {
            int a = FLD(fin+0), b = FLD(fin+1), c = FLD(fin+2), d = FLD(fin+3);
            v = imin(imin(a, b), imin(c, d));
            if (v >= cbase + 1) break;
            --budget; __builtin_amdgcn_s_sleep(2);
          }
          s_fin = v; f0 = v; f1 = v; f2 = v; f3 = v;
        }
      }
      __syncthreads();
      if (isX) {
        u64 r0 = FLD(raddr(tbase) + tid);
        u16* xd = xstA[tbase & 1];
#pragma unroll
        for (int p = 0; p < 4; ++p) xd[(srow + p) * 72 + scol] = (u16)(r0 >> (16 * p));
      }
    }
    if (P == 0 && isX) {
      int tx = (tbase < 256) ? tbase : 0;
#pragma unroll
      for (int kc = 0; kc < 4; ++kc) cfx[kc] = ld8(ctx_, (brow*256 + tx)*128 + kc*32 + hi*8);
    }

#pragma unroll 1
    for (int k = 0; k < NC; ++k) {
      const int t0 = tbase + k * CH;
      const int ck = cbase + k;
      const int fneed = ck + 2 - ((dec && k == NC - 1) ? 1 : 0);
      const int need  = (credOn && k >= RC) ? (ck + 1 - RC) : 0;
      u64 ra[CH];
#pragma unroll
      for (int j = 0; j < CH; ++j) ra[j] = 0;

#pragma unroll
      for (int tt = 0; tt < CH; ++tt) {
        const int t = t0 + tt;
        lds_barrier();   // slot start: all slot t-1 writes visible

        if (tt == 0) {
          int vf = s_fin, vc = s_cn;
          const bool slowF = (P > 0)  && (vf < fneed);
          const bool slowC = (P < 31) && (need > 0) && (vc < need);
          if (slowF || slowC) {
            if (tid == 0) {
              if (slowF) {
                int v = 0;
                while (budget > 0) {
                  int a = FLD(fin+0), b = FLD(fin+1), c = FLD(fin+2), d = FLD(fin+3);
                  v = imin(imin(a, b), imin(c, d));
                  if (v >= fneed) break;
                  --budget; __builtin_amdgcn_s_sleep(2);
                }
                s_fin = v; f0 = v; f1 = v; f2 = v; f3 = v;
              }
              if (slowC) {
                int v = 0;
                while (budget > 0) {
                  int a = FLD(cnext+0), b = FLD(cnext+1), c = FLD(cnext+2), d = FLD(cnext+3);
                  v = imin(imin(a, b), imin(c, d));
                  if (v >= need) break;
                  --budget; __builtin_amdgcn_s_sleep(2);
                }
                s_cn = v; c0 = v; c1 = v; c2 = v; c3 = v;
              }
            }
            lds_barrier();
          }
          if (isX && P > 0) {   // prime records t0+1..t0+CH
#pragma unroll
            for (int j = 0; j < CH; ++j)
              if (t0 + 1 + j <= 511) ra[j] = FLD(raddr(t0 + 1 + j) + tid);
          }
        }

        if (isX) {
          // per-slot probe publish (last slot's reads) + reissue
          if (tid == 0) {
            if (P > 0)  s_fin = imin(imin(f0, f1), imin(f2, f3));
            if (P < 31 && credOn) s_cn = imin(imin(c0, c1), imin(c2, c3));
            if (P > 0)  { f0 = FLD(fin+0); f1 = FLD(fin+1); f2 = FLD(fin+2); f3 = FLD(fin+3); }
            if (P < 31 && credOn) { c0 = FLD(cnext+0); c1 = FLD(cnext+1); c2 = FLD(cnext+2); c3 = FLD(cnext+3); }
          }

          // ================= layer A(t) =================
          f32x4 ar, az, ain, ahn;
          { float v;
            v = brzA[0]; ar  = (f32x4){v,v,v,v};
            v = brzA[1]; az  = (f32x4){v,v,v,v};
            v = binA;    ain = (f32x4){v,v,v,v};
            v = bhnA;    ahn = (f32x4){v,v,v,v}; }
          const u16* hsA = hbA[(t + 1) & 1];
#pragma unroll
          for (int kc = 0; kc < 2; ++kc) {
            short8 hA = *(const short8*)(hsA + lo*72 + kc*32 + hi*8);
            ar  = __builtin_amdgcn_mfma_f32_16x16x32_bf16(hA, WF(oWhA0, kc), ar,  0, 0, 0);
            az  = __builtin_amdgcn_mfma_f32_16x16x32_bf16(hA, WF(oWhA1, kc), az,  0, 0, 0);
            ahn = __builtin_amdgcn_mfma_f32_16x16x32_bf16(hA, WF(oWhA2, kc), ahn, 0, 0, 0);
          }
          short8 xfA[4] = {zf8, zf8, zf8, zf8};
          if (P > 0) {
            const u16* xs = xstA[t & 1];
#pragma unroll
            for (int kc = 0; kc < 2; ++kc)
              xfA[kc] = *(const short8*)(xs + lo*72 + kc*32 + hi*8);
          } else {
#pragma unroll
            for (int kc = 0; kc < 4; ++kc) xfA[kc] = cfx[kc];
          }
          if (!(P == 0 && t == 256)) {
#pragma unroll
            for (int kc = 0; kc < 4; ++kc) {
              if (kc < NKCA) {
                ar  = __builtin_amdgcn_mfma_f32_16x16x32_bf16(xfA[kc], WF(oWiA0, kc), ar,  0, 0, 0);
                az  = __builtin_amdgcn_mfma_f32_16x16x32_bf16(xfA[kc], WF(oWiA1, kc), az,  0, 0, 0);
                ain = __builtin_amdgcn_mfma_f32_16x16x32_bf16(xfA[kc], WF(oWiA2, kc), ain, 0, 0, 0);
              }
            }
          }
          u16 hAb[4];
#pragma unroll
          for (int p = 0; p < 4; ++p) {
            float r = sigm(ar[p]);
            float z = sigm(az[p]);
            float n = tanhf_(ain[p] + r * ahn[p]);
            float h = n + z * (hprevA[p] - n);
            h = fminf(1.f, fmaxf(-1.f, h));
            hprevA[p] = h;
            hAb[p] = f2bf(h);
          }
          {
            u16* hd = hbA[t & 1];
#pragma unroll
            for (int p = 0; p < 4; ++p)
              hd[(hi*4 + p) * 72 + qg*16 + lo] = hAb[p];
          }
          if (P == 0) {              // prefetch ctx for t+1
            int tn = t + 1;
            if (tn <= 511) {
              int tx = (tn < 256) ? tn : ((tn == 256) ? 0 : tn - 257);
#pragma unroll
              for (int kc = 0; kc < 4; ++kc)
                cfx[kc] = ld8(ctx_, (brow*256 + tx)*128 + kc*32 + hi*8);
            }
          }
          if (P > 0 && t < 511) {    // stage x(t+1) -> xstA[(t+1)&1]
            u64 r = ra[tt];
            u16* xd = xstA[(t + 1) & 1];
#pragma unroll
            for (int p = 0; p < 4; ++p) xd[(srow + p) * 72 + scol] = (u16)(r >> (16 * p));
          }
          if (tt == CH - 1 && P > 0 && credOn) {   // consumer credit (per X wave)
            DRAIN0();
            if (lane == 0) FST(cself + qg, ck + 1);
          }
        } else {
          // ================= Y: flag first (drain covers >=1-slot-old stores)
          constexpr int FO = (CH >= 2) ? 1 : 0;
          if (P < 31 && tt == FO && k > ((CH == 1) ? 1 : 0)) {
            DRAIN0();
            if (lane == 0) FST(fout + qg, ck - ((CH == 1) ? 1 : 0));
          }
          if (P == 31 && dec && t >= 258) do_proj(t - 2, hbB[t & 1]);
          if (t - 1 >= tbase) doB(t - 1);
        }
      }
    }

    // ---- tail slot: Y computes B(tbase+255)
    lds_barrier();
    if (!isX) {
      doB(tbase + 255);
      if (P < 31) {
        DRAIN0();
        if (lane == 0) FST(fout + qg, cbase + NC);   // all span chunks complete
      }
    }
  };

  {
    const int NCe = 256 / CHE;
    int RCe = (RE >= 256) ? NCe : (RE / CHE) - 2; if (RCe < 1) RCe = 1;
    span(IC<CHE>{}, 0, 0, RCe, false);             // encoder
    __syncthreads();
    load_phase(1);                                 // decoder weights -> LDS
    __syncthreads();
    int RCd = (RW >= 256) ? (256 / CHD) : (RW / CHD) - 2; if (RCd < 1) RCd = 1;
    span(IC<CHD>{}, 256, NCe, RCd, true);          // decoder
  }

  // ---- epilogue: projections of steps 510, 511
  lds_barrier();
  if (P == 31 && !isX) {
    do_proj(510, hbB[0]);
    do_proj(511, hbB[1]);
  }
}

extern "C" void kernel_launch(void* const* d_in, const int* in_sizes, int n_in,
                              void* d_out, int out_size, void* d_ws, size_t ws_size,
                              hipStream_t stream)
{
  char* ws = (char*)d_ws;
  int* pflag = (int*)ws;                    // 248 edges x 64B per-wave flag lines
  int* cflag = (int*)(ws + 32768);          // 256 x 64B per-wave credit lines
  char* ringbase = ws + 65536;

  const size_t per_slot = (size_t)31 * 8 * 2048;  // one ring step across all 31x8 edges
  size_t avail = (ws_size > 65536) ? ws_size - 65536 : 0;

  int RE, RW;
  u64 *ringE, *ringD;
  int Rh = 0;
  for (int r = 256; r >= 16; r >>= 1)
    if ((size_t)(2 * r) * per_slot <= avail) { Rh = r; break; }
  if (Rh) {                                  // both rings in workspace
    RE = RW = Rh;
    ringE = (u64*)ringbase;
    ringD = (u64*)(ringbase + (size_t)Rh * per_slot);
  } else {                                   // fallback: encoder ring borrows d_out
    int Rw = 1;
    for (int r = 256; r >= 1; r >>= 1)
      if ((size_t)r * per_slot <= avail) { Rw = r; break; }
    RW = Rw;
    int Re = 1;
    for (int r = 16; r >= 1; r >>= 1)
      if ((size_t)r * per_slot <= (size_t)out_size) { Re = r; break; }
    RE = Re;
    ringE = (u64*)d_out;
    ringD = (u64*)ringbase;
  }
  const int CHe = (RE >= 32) ? 4 : ((RE >= 16) ? 2 : 1);
  const int CHd = (RW >= 32) ? 4 : ((RW >= 16) ? 2 : 1);

  const int dyn = 122880;   // 120KB weight tiles in dynamic LDS
  static int attr_done = 0;
  if (!attr_done) {
    hipFuncSetAttribute(reinterpret_cast<const void*>(gru_pipeline<4,4>),
                        hipFuncAttributeMaxDynamicSharedMemorySize, dyn);
    hipFuncSetAttribute(reinterpret_cast<const void*>(gru_pipeline<2,4>),
                        hipFuncAttributeMaxDynamicSharedMemorySize, dyn);
    hipFuncSetAttribute(reinterpret_cast<const void*>(gru_pipeline<2,2>),
                        hipFuncAttributeMaxDynamicSharedMemorySize, dyn);
    hipFuncSetAttribute(reinterpret_cast<const void*>(gru_pipeline<2,1>),
                        hipFuncAttributeMaxDynamicSharedMemorySize, dyn);
    hipFuncSetAttribute(reinterpret_cast<const void*>(gru_pipeline<1,1>),
                        hipFuncAttributeMaxDynamicSharedMemorySize, dyn);
    attr_done = 1;
  }

  hipMemsetAsync(ws, 0, 65536, stream);     // zero flags every launch

#define LAUNCH(CE, CD)                                                     \
  gru_pipeline<CE, CD><<<256, 512, dyn, stream>>>(                         \
      d_in[0], d_in[1], d_in[2], d_in[3], d_in[4], d_in[5],                \
      d_in[6], d_in[7], d_in[8], d_in[9], d_in[10], d_in[11], d_in[12],    \
      d_out, pflag, cflag, ringE, ringD, RE, RW)

  if      (CHe == 4 && CHd == 4) LAUNCH(4, 4);
  else if (CHe == 2 && CHd == 4) LAUNCH(2, 4);
  else if (CHe == 2 && CHd == 2) LAUNCH(2, 2);
  else if (CHe == 2 && CHd == 1) LAUNCH(2, 1);
  else                           LAUNCH(1, 1);
#undef LAUNCH
  (void)in_sizes; (void)n_in;
}

// Round 7
// 1762.501 us; speedup vs baseline: 1.0558x; 1.0558x over previous
//
#include <hip/hip_runtime.h>
#include <stdint.h>

typedef uint16_t u16;
typedef unsigned long long u64;
typedef __attribute__((ext_vector_type(8))) short short8;   // 8 x bf16 bits (4 VGPRs)
typedef __attribute__((ext_vector_type(4))) float f32x4;

#define SCOPE __HIP_MEMORY_SCOPE_AGENT
#define FSTRIDE 16   // ints per edge flag line (64B): 4 per-wave flags
#define FLD(p) __hip_atomic_load((p), __ATOMIC_RELAXED, SCOPE)
#define FST(p, v) __hip_atomic_store((p), (v), __ATOMIC_RELAXED, SCOPE)

template <int N> struct IC { static constexpr int value = N; };

static __device__ __forceinline__ float bf2f(u16 b) {
  union { uint32_t u; float f; } x; x.u = ((uint32_t)b) << 16; return x.f;
}
static __device__ __forceinline__ u16 f2bf(float f) {
  union { float f; uint32_t u; } x; x.f = f;
  uint32_t u = x.u;
  u += 0x7fffu + ((u >> 16) & 1u);   // RTNE
  return (u16)(u >> 16);
}
// inf-safe: exp(+inf)->inf, 1+inf=inf, rcp(inf)=0; exp(-inf)->0.
static __device__ __forceinline__ float sigm(float x) {
  return __builtin_amdgcn_rcpf(1.f + __expf(-x));
}
static __device__ __forceinline__ float tanhf_(float x) {
  return 1.f - 2.f * __builtin_amdgcn_rcpf(1.f + __expf(2.f * x));
}
// LDS-only barrier: does NOT drain vmcnt.
static __device__ __forceinline__ void lds_barrier() {
  asm volatile("s_waitcnt lgkmcnt(0)\n\ts_barrier" ::: "memory");
}
#define DRAIN0() asm volatile("s_waitcnt vmcnt(0)" ::: "memory")
#define DRAIN1() asm volatile("s_waitcnt vmcnt(1)" ::: "memory")
static __device__ __forceinline__ int imin(int a, int b) { return a < b ? a : b; }

// R16: slot-granular producer flags (counted-vmcnt release) on R14's skeleton.
// Model fit (R13/R14/R15): total = 512*period + 31*lag*period with period
// ~2.2us in ALL rounds; R15's regression == its CH4 lag increase (+93 slots
// * 2.2 = +205us). So: fill term (hops x lag) is protocol-determined and
// attackable. R16 keeps R14 (CH=2, X/Y skew, chunk prime, chunk credit) and
// changes ONLY the flag: Y issues ring-store(t-1) in slot t, then
// s_waitcnt vmcnt(1) (waits only the >=1-slot-old store: zero exposed RTT),
// posts flag = t-1 ("records <= t-2 visible"). fneed slot-valued (t0+CH+1);
// probes refreshed every slot. Lag ~8 -> ~5 slots/hop; fill 546 -> ~340us.
// MFMA 16x16x32 bf16 layouts (m89-verified):
//   A-frag: lane holds A[m=lane&15][k=(lane>>4)*8+j]
//   B-frag: lane holds B[k=(lane>>4)*8+j][n=lane&15]  (W row-major (N,K))
//   C/D: reg p -> (row=(lane>>4)*4+p, col=lane&15)
#define OFF_WHA 0
#define OFF_WHB 12288
#define OFF_WIB 24576
#define OFF_WIA 36864
#define OFF_WO  49152

template <int CHE, int CHD>
__global__ __launch_bounds__(512, 1) void gru_pipeline(
    const void* ctx_,
    const void* eWih0_, const void* eWih_, const void* eWhh_,
    const void* ebih_,  const void* ebhh_,
    const void* dWih0_, const void* dWih_, const void* dWhh_,
    const void* dbih_,  const void* dbhh_,
    const void* Wo_,    const void* bo_,   void* out_,
    int* __restrict__ pflag, int* __restrict__ cflag,
    u64* __restrict__ ringE, u64* __restrict__ ringD, int RE, int RW)
{
  const int tid  = threadIdx.x;
  const bool isX = (tid < 256);   // X: layer A of step t; Y: layer B of step t-1
  const int lane = tid & 63;
  const int qg   = (tid >> 6) & 3;  // wave within group
  const int w8   = tid >> 6;        // 0..7
  const int lo   = lane & 15;
  const int hi   = lane >> 4;
  const int blk  = blockIdx.x;
  const int P    = blk >> 3;      // layer pair 0..31
  const int g    = blk & 7;       // batch chunk (16 rows)
  const int LA   = 2 * P;
  const int NKCA = (P == 0) ? 4 : 2;

  extern __shared__ __align__(16) u16 dynlds[];   // weight tiles (120KB)

  __shared__ __align__(16) u16 hbA[2][16 * 72];
  __shared__ __align__(16) u16 hbB[2][16 * 72];
  __shared__ __align__(16) u16 xstA[2][16 * 72];
  __shared__ int s_cnt, s_fin, s_cn;
  if (tid == 0) { s_cnt = 0; s_fin = 0; s_cn = 0; }
  for (int i = tid; i < 16 * 72; i += 512) {
    hbA[0][i] = 0; hbA[1][i] = 0; hbB[0][i] = 0; hbB[1][i] = 0;
    xstA[0][i] = 0; xstA[1][i] = 0;
  }
  __syncthreads();
  {  // dtype probe: even u16s of enc_bih
    u16 v = ((const u16*)ebih_)[2 * (tid & 255)];
    int e = (v >> 7) & 0xFF;
    if (e >= 100 && e <= 126 && isX) atomicAdd(&s_cnt, 1);
  }
  __syncthreads();
  const bool bf = (s_cnt >= 128);   // true: bf16 tensors; false: fp32

  auto ld8 = [&](const void* p, int idx) -> short8 {
    if (bf) return *(const short8*)((const u16*)p + idx);
    const float* f = (const float*)p + idx;
    short8 r;
#pragma unroll
    for (int j = 0; j < 8; ++j) r[j] = (short)f2bf(f[j]);
    return r;
  };
  auto ld1 = [&](const void* p, int idx) -> float {
    return bf ? bf2f(((const u16*)p)[idx]) : ((const float*)p)[idx];
  };

  const int T0 = qg, T1 = 4 + qg, T2 = 8 + qg;

  short8 zf8 = {0,0,0,0,0,0,0,0};
  float  bov[2] = {0.f, 0.f};
  float brzA[2] = {0,0}, binA = 0, bhnA = 0;
  float brzB[2] = {0,0}, binB = 0, bhnB = 0;

  // ---- cooperative stage of a row-major (NT*16 x KC*32) matrix into LDS tiles
  auto stage_w = [&](int offU16, const void* W, int gidx0, int NT, int KC, int K) {
    for (int nt = w8; nt < NT; nt += 8)
      for (int kc = 0; kc < KC; ++kc) {
        short8 v = ld8(W, gidx0 + (nt*16 + lo)*K + kc*32 + hi*8);
        *(short8*)(dynlds + offU16 + (nt*KC + kc)*512 + lane*8) = v;
      }
  };

  auto load_phase = [&](int ph) {
    const void* WH  = ph ? dWhh_ : eWhh_;
    const void* WIs = ph ? dWih_ : eWih_;
    const void* WI0 = ph ? dWih0_ : eWih0_;
    const void* bi  = ph ? dbih_ : ebih_;
    const void* bh  = ph ? dbhh_ : ebhh_;
    stage_w(OFF_WHA, WH, LA*192*64, 12, 2, 64);
    stage_w(OFF_WHB, WH, (LA+1)*192*64, 12, 2, 64);
    stage_w(OFF_WIB, WIs, LA*192*64, 12, 2, 64);   // Wih[LB-1] = Wih[LA]
    if (LA == 0) stage_w(OFF_WIA, WI0, 0, 12, 4, 128);
    else         stage_w(OFF_WIA, WIs, (LA-1)*192*64, 12, 2, 64);
    if (isX) {
      brzA[0] = ld1(bi, LA*192 + T0*16 + lo) + ld1(bh, LA*192 + T0*16 + lo);
      brzA[1] = ld1(bi, LA*192 + T1*16 + lo) + ld1(bh, LA*192 + T1*16 + lo);
      binA    = ld1(bi, LA*192 + T2*16 + lo);
      bhnA    = ld1(bh, LA*192 + T2*16 + lo);
    } else {
      const int LB = LA + 1;
      brzB[0] = ld1(bi, LB*192 + T0*16 + lo) + ld1(bh, LB*192 + T0*16 + lo);
      brzB[1] = ld1(bi, LB*192 + T1*16 + lo) + ld1(bh, LB*192 + T1*16 + lo);
      binB    = ld1(bi, LB*192 + T2*16 + lo);
      bhnB    = ld1(bh, LB*192 + T2*16 + lo);
    }
  };
  load_phase(0);
  if (P == 31) {   // Wo staged once (OFF_WO untouched by load_phase(1): KCA=2)
    stage_w(OFF_WO, Wo_, 0, 8, 2, 64);
    if (!isX) { bov[0] = ld1(bo_, 32*qg + lo); bov[1] = ld1(bo_, 32*qg + 16 + lo); }
  }

  // ---- precomputed LDS u16 offsets for weight fragments
  const int oWhA0 = OFF_WHA + T0*1024 + lane*8;
  const int oWhA1 = OFF_WHA + T1*1024 + lane*8;
  const int oWhA2 = OFF_WHA + T2*1024 + lane*8;
  const int oWhB0 = OFF_WHB + T0*1024 + lane*8;
  const int oWhB1 = OFF_WHB + T1*1024 + lane*8;
  const int oWhB2 = OFF_WHB + T2*1024 + lane*8;
  const int oWiB0 = OFF_WIB + T0*1024 + lane*8;
  const int oWiB1 = OFF_WIB + T1*1024 + lane*8;
  const int oWiB2 = OFF_WIB + T2*1024 + lane*8;
  const int oWiA0 = OFF_WIA + T0*(NKCA*512) + lane*8;
  const int oWiA1 = OFF_WIA + T1*(NKCA*512) + lane*8;
  const int oWiA2 = OFF_WIA + T2*(NKCA*512) + lane*8;
  const int oWo0  = OFF_WO + (2*qg + 0)*1024 + lane*8;
  const int oWo1  = OFF_WO + (2*qg + 1)*1024 + lane*8;

  auto WF = [&](int off, int kc) -> short8 {   // one ds_read_b128, kc -> imm
    return *(const short8*)(dynlds + off + kc*512);
  };

  auto do_proj = [&](int tprev, const u16* hs) {   // Y-group only
    f32x4 pacc[2];
#pragma unroll
    for (int ct = 0; ct < 2; ++ct) { float v = bov[ct]; f32x4 tv = {v,v,v,v}; pacc[ct] = tv; }
#pragma unroll
    for (int kc = 0; kc < 2; ++kc) {
      short8 hA = *(const short8*)(hs + lo*72 + kc*32 + hi*8);
      pacc[0] = __builtin_amdgcn_mfma_f32_16x16x32_bf16(hA, WF(oWo0, kc), pacc[0], 0, 0, 0);
      pacc[1] = __builtin_amdgcn_mfma_f32_16x16x32_bf16(hA, WF(oWo1, kc), pacc[1], 0, 0, 0);
    }
#pragma unroll
    for (int ct = 0; ct < 2; ++ct) {
      int n = 32*qg + 16*ct + lo;
#pragma unroll
      for (int p = 0; p < 4; ++p) {
        int b = 16*g + hi*4 + p;
        size_t idx = ((size_t)b * 256 + (tprev - 256)) * 128 + n;
        float v = fminf(64.f, fmaxf(-64.f, pacc[ct][p]));
        if (bf) ((u16*)out_)[idx] = f2bf(v);
        else    ((float*)out_)[idx] = v;
      }
    }
  };

  float hprevA[4] = {0,0,0,0}, hprevB[4] = {0,0,0,0};
  const int brow = 16*g + lo;   // P0 context row

  const int eIn  = (P > 0 ? P - 1 : 0) * 8 + g;
  const int eOut = (P < 31 ? P : 30) * 8 + g;
  int* fin   = pflag + eIn  * FSTRIDE;
  int* fout  = pflag + eOut * FSTRIDE;
  int* cself = cflag + (P * 8 + g) * FSTRIDE;
  int* cnext = cflag + ((P < 31 ? P + 1 : 31) * 8 + g) * FSTRIDE;

  // ring address of record t (consumer side / producer side)
  auto raddr = [&](int t) -> const u64* {
    return (t < 256)
      ? (ringE + (size_t)eIn * ((size_t)RE * 256) + (size_t)(t & (RE-1)) * 256)
      : (ringD + (size_t)eIn * ((size_t)RW * 256) + (size_t)((t-256) & (RW-1)) * 256);
  };
  auto waddr = [&](int t) -> u64* {
    return (t < 256)
      ? (ringE + (size_t)eOut * ((size_t)RE * 256) + (size_t)(t & (RE-1)) * 256)
      : (ringD + (size_t)eOut * ((size_t)RW * 256) + (size_t)((t-256) & (RW-1)) * 256);
  };

  int budget = 1 << 22;   // anti-hang
  const int srow = 4 * (tid & 3);   // X record unpack: row quad
  const int scol = tid >> 2;        // X record unpack: h column (tid<256)

  int f0=0,f1=0,f2=0,f3=0, c0=0,c1=0,c2=0,c3=0;   // tid0 probe holds (1-slot stale)
  short8 cfx[4] = {zf8, zf8, zf8, zf8};           // P0 ctx prefetch (X)

  // ---- layer-B step (Y): compute B(s), write hbB[s&1], ring-store record(s)
  auto doB = [&](int s) {
    f32x4 br, bz, bin2, bhn;
    { float v;
      v = brzB[0]; br   = (f32x4){v,v,v,v};
      v = brzB[1]; bz   = (f32x4){v,v,v,v};
      v = binB;    bin2 = (f32x4){v,v,v,v};
      v = bhnB;    bhn  = (f32x4){v,v,v,v}; }
    const u16* hsB = hbB[(s + 1) & 1];   // h_B(s-1)
    const u16* xsB = hbA[s & 1];         // h_A(s)
#pragma unroll
    for (int kc = 0; kc < 2; ++kc) {
      short8 hB = *(const short8*)(hsB + lo*72 + kc*32 + hi*8);
      short8 xB = *(const short8*)(xsB + lo*72 + kc*32 + hi*8);
      br   = __builtin_amdgcn_mfma_f32_16x16x32_bf16(hB, WF(oWhB0, kc), br,   0, 0, 0);
      bz   = __builtin_amdgcn_mfma_f32_16x16x32_bf16(hB, WF(oWhB1, kc), bz,   0, 0, 0);
      bhn  = __builtin_amdgcn_mfma_f32_16x16x32_bf16(hB, WF(oWhB2, kc), bhn,  0, 0, 0);
      br   = __builtin_amdgcn_mfma_f32_16x16x32_bf16(xB, WF(oWiB0, kc), br,   0, 0, 0);
      bz   = __builtin_amdgcn_mfma_f32_16x16x32_bf16(xB, WF(oWiB1, kc), bz,   0, 0, 0);
      bin2 = __builtin_amdgcn_mfma_f32_16x16x32_bf16(xB, WF(oWiB2, kc), bin2, 0, 0, 0);
    }
    u16 hBb[4];
#pragma unroll
    for (int p = 0; p < 4; ++p) {
      float r = sigm(br[p]);
      float z = sigm(bz[p]);
      float n = tanhf_(bin2[p] + r * bhn[p]);
      float h = n + z * (hprevB[p] - n);
      h = fminf(1.f, fmaxf(-1.f, h));
      hprevB[p] = h;
      hBb[p] = f2bf(h);
    }
    u16* hd = hbB[s & 1];
#pragma unroll
    for (int p = 0; p < 4; ++p)
      hd[(hi*4 + p) * 72 + qg*16 + lo] = hBb[p];
    if (P < 31) {
      u64 da = (u64)hBb[0] | ((u64)hBb[1] << 16) | ((u64)hBb[2] << 32) | ((u64)hBb[3] << 48);
      FST(waddr(s) + (16*qg + lo)*4 + hi, da);
    }
  };

  __syncthreads();   // weight tiles + buffers visible

  // ---------------- span: slots t = tbase..tbase+255 (X:A(t), Y:B(t-1)) + tail
  auto span = [&](auto chc, const int tbase, const int cbase, const int RC, const bool dec) {
    constexpr int CH = decltype(chc)::value;
    const int NC = 256 / CH;
    const bool credOn = (RC < NC);

    // ---- prologue: wait (slot-valued flag) + stage x(tbase); P0: ctx prefetch
    if (P > 0) {
      if (tid == 0) {
        int v = s_fin;
        if (v < tbase + 1) {
          while (budget > 0) {
            int a = FLD(fin+0), b = FLD(fin+1), c = FLD(fin+2), d = FLD(fin+3);
            v = imin(imin(a, b), imin(c, d));
            if (v >= tbase + 1) break;
            --budget; __builtin_amdgcn_s_sleep(2);
          }
          s_fin = v; f0 = v; f1 = v; f2 = v; f3 = v;
        }
      }
      __syncthreads();
      if (isX) {
        u64 r0 = FLD(raddr(tbase) + tid);
        u16* xd = xstA[tbase & 1];
#pragma unroll
        for (int p = 0; p < 4; ++p) xd[(srow + p) * 72 + scol] = (u16)(r0 >> (16 * p));
      }
    }
    if (P == 0 && isX) {
      int tx = (tbase < 256) ? tbase : 0;
#pragma unroll
      for (int kc = 0; kc < 4; ++kc) cfx[kc] = ld8(ctx_, (brow*256 + tx)*128 + kc*32 + hi*8);
    }

#pragma unroll 1
    for (int k = 0; k < NC; ++k) {
      const int t0 = tbase + k * CH;
      const int ck = cbase + k;
      const int fneed = imin(512, t0 + CH + 1);       // slot-valued
      const int need  = (credOn && k >= RC) ? (ck + 1 - RC) : 0;
      u64 ra[CH];
#pragma unroll
      for (int j = 0; j < CH; ++j) ra[j] = 0;

#pragma unroll
      for (int tt = 0; tt < CH; ++tt) {
        const int t = t0 + tt;
        lds_barrier();   // slot start: all slot t-1 writes visible

        if (tt == 0) {
          int vf = s_fin, vc = s_cn;
          const bool slowF = (P > 0)  && (vf < fneed);
          const bool slowC = (P < 31) && (need > 0) && (vc < need);
          if (slowF || slowC) {
            if (tid == 0) {
              if (slowF) {
                int v = 0;
                while (budget > 0) {
                  int a = FLD(fin+0), b = FLD(fin+1), c = FLD(fin+2), d = FLD(fin+3);
                  v = imin(imin(a, b), imin(c, d));
                  if (v >= fneed) break;
                  --budget; __builtin_amdgcn_s_sleep(2);
                }
                s_fin = v; f0 = v; f1 = v; f2 = v; f3 = v;
              }
              if (slowC) {
                int v = 0;
                while (budget > 0) {
                  int a = FLD(cnext+0), b = FLD(cnext+1), c = FLD(cnext+2), d = FLD(cnext+3);
                  v = imin(imin(a, b), imin(c, d));
                  if (v >= need) break;
                  --budget; __builtin_amdgcn_s_sleep(2);
                }
                s_cn = v; c0 = v; c1 = v; c2 = v; c3 = v;
              }
            }
            lds_barrier();
          }
          if (isX && P > 0) {   // prime records t0+1..t0+CH
#pragma unroll
            for (int j = 0; j < CH; ++j)
              if (t0 + 1 + j <= 511) ra[j] = FLD(raddr(t0 + 1 + j) + tid);
          }
        }

        if (isX) {
          // per-slot probe publish (last slot's reads) + reissue
          if (tid == 0) {
            if (P > 0)  s_fin = imin(imin(f0, f1), imin(f2, f3));
            if (P < 31 && credOn) s_cn = imin(imin(c0, c1), imin(c2, c3));
            if (P > 0)  { f0 = FLD(fin+0); f1 = FLD(fin+1); f2 = FLD(fin+2); f3 = FLD(fin+3); }
            if (P < 31 && credOn) { c0 = FLD(cnext+0); c1 = FLD(cnext+1); c2 = FLD(cnext+2); c3 = FLD(cnext+3); }
          }

          // ================= layer A(t) =================
          f32x4 ar, az, ain, ahn;
          { float v;
            v = brzA[0]; ar  = (f32x4){v,v,v,v};
            v = brzA[1]; az  = (f32x4){v,v,v,v};
            v = binA;    ain = (f32x4){v,v,v,v};
            v = bhnA;    ahn = (f32x4){v,v,v,v}; }
          const u16* hsA = hbA[(t + 1) & 1];
#pragma unroll
          for (int kc = 0; kc < 2; ++kc) {
            short8 hA = *(const short8*)(hsA + lo*72 + kc*32 + hi*8);
            ar  = __builtin_amdgcn_mfma_f32_16x16x32_bf16(hA, WF(oWhA0, kc), ar,  0, 0, 0);
            az  = __builtin_amdgcn_mfma_f32_16x16x32_bf16(hA, WF(oWhA1, kc), az,  0, 0, 0);
            ahn = __builtin_amdgcn_mfma_f32_16x16x32_bf16(hA, WF(oWhA2, kc), ahn, 0, 0, 0);
          }
          short8 xfA[4] = {zf8, zf8, zf8, zf8};
          if (P > 0) {
            const u16* xs = xstA[t & 1];
#pragma unroll
            for (int kc = 0; kc < 2; ++kc)
              xfA[kc] = *(const short8*)(xs + lo*72 + kc*32 + hi*8);
          } else {
#pragma unroll
            for (int kc = 0; kc < 4; ++kc) xfA[kc] = cfx[kc];
          }
          if (!(P == 0 && t == 256)) {
#pragma unroll
            for (int kc = 0; kc < 4; ++kc) {
              if (kc < NKCA) {
                ar  = __builtin_amdgcn_mfma_f32_16x16x32_bf16(xfA[kc], WF(oWiA0, kc), ar,  0, 0, 0);
                az  = __builtin_amdgcn_mfma_f32_16x16x32_bf16(xfA[kc], WF(oWiA1, kc), az,  0, 0, 0);
                ain = __builtin_amdgcn_mfma_f32_16x16x32_bf16(xfA[kc], WF(oWiA2, kc), ain, 0, 0, 0);
              }
            }
          }
          u16 hAb[4];
#pragma unroll
          for (int p = 0; p < 4; ++p) {
            float r = sigm(ar[p]);
            float z = sigm(az[p]);
            float n = tanhf_(ain[p] + r * ahn[p]);
            float h = n + z * (hprevA[p] - n);
            h = fminf(1.f, fmaxf(-1.f, h));
            hprevA[p] = h;
            hAb[p] = f2bf(h);
          }
          {
            u16* hd = hbA[t & 1];
#pragma unroll
            for (int p = 0; p < 4; ++p)
              hd[(hi*4 + p) * 72 + qg*16 + lo] = hAb[p];
          }
          if (P == 0) {              // prefetch ctx for t+1
            int tn = t + 1;
            if (tn <= 511) {
              int tx = (tn < 256) ? tn : ((tn == 256) ? 0 : tn - 257);
#pragma unroll
              for (int kc = 0; kc < 4; ++kc)
                cfx[kc] = ld8(ctx_, (brow*256 + tx)*128 + kc*32 + hi*8);
            }
          }
          if (P > 0 && t < 511) {    // stage x(t+1) -> xstA[(t+1)&1]
            u64 r = ra[tt];
            u16* xd = xstA[(t + 1) & 1];
#pragma unroll
            for (int p = 0; p < 4; ++p) xd[(srow + p) * 72 + scol] = (u16)(r >> (16 * p));
          }
          if (tt == CH - 1 && P > 0 && credOn) {   // consumer credit (per X wave)
            DRAIN0();
            if (lane == 0) FST(cself + qg, ck + 1);
          }
        } else {
          // ================= Y: proj + B(t-1) + slot-granular flag =================
          if (P == 31 && dec && t >= 258) do_proj(t - 2, hbB[t & 1]);
          if (t - 1 >= tbase) doB(t - 1);
          // slot flag: after issuing store(t-1), wait all but it (store(t-2)
          // is >=1 slot old -> no exposed RTT), post "records <= t-2 visible".
          if (P < 31 && t >= tbase + 2) {
            DRAIN1();
            if (lane == 0) FST(fout + qg, t - 1);
          }
        }
      }
    }

    // ---- tail slot: Y computes B(tbase+255)
    lds_barrier();
    if (!isX) {
      doB(tbase + 255);
      if (P < 31) {
        DRAIN0();
        if (lane == 0) FST(fout + qg, tbase + 256);   // all span records visible
      }
    }
  };

  {
    const int NCe = 256 / CHE;
    int RCe = (RE >= 256) ? NCe : (RE / CHE) - 2; if (RCe < 1) RCe = 1;
    span(IC<CHE>{}, 0, 0, RCe, false);             // encoder
    __syncthreads();
    load_phase(1);                                 // decoder weights -> LDS
    __syncthreads();
    int RCd = (RW >= 256) ? (256 / CHD) : (RW / CHD) - 2; if (RCd < 1) RCd = 1;
    span(IC<CHD>{}, 256, NCe, RCd, true);          // decoder
  }

  // ---- epilogue: projections of steps 510, 511
  lds_barrier();
  if (P == 31 && !isX) {
    do_proj(510, hbB[0]);
    do_proj(511, hbB[1]);
  }
}

extern "C" void kernel_launch(void* const* d_in, const int* in_sizes, int n_in,
                              void* d_out, int out_size, void* d_ws, size_t ws_size,
                              hipStream_t stream)
{
  char* ws = (char*)d_ws;
  int* pflag = (int*)ws;                    // 248 edges x 64B per-wave flag lines
  int* cflag = (int*)(ws + 32768);          // 256 x 64B per-wave credit lines
  char* ringbase = ws + 65536;

  const size_t per_slot = (size_t)31 * 8 * 2048;  // one ring step across all 31x8 edges
  size_t avail = (ws_size > 65536) ? ws_size - 65536 : 0;

  int RE, RW;
  u64 *ringE, *ringD;
  int Rh = 0;
  for (int r = 256; r >= 16; r >>= 1)
    if ((size_t)(2 * r) * per_slot <= avail) { Rh = r; break; }
  if (Rh) {                                  // both rings in workspace
    RE = RW = Rh;
    ringE = (u64*)ringbase;
    ringD = (u64*)(ringbase + (size_t)Rh * per_slot);
  } else {                                   // fallback: encoder ring borrows d_out
    int Rw = 1;
    for (int r = 256; r >= 1; r >>= 1)
      if ((size_t)r * per_slot <= avail) { Rw = r; break; }
    RW = Rw;
    int Re = 1;
    for (int r = 16; r >= 1; r >>= 1)
      if ((size_t)r * per_slot <= (size_t)out_size) { Re = r; break; }
    RE = Re;
    ringE = (u64*)d_out;
    ringD = (u64*)ringbase;
  }
  const int CHe = (RE >= 8) ? 2 : 1;
  const int CHd = (RW >= 8) ? 2 : 1;

  const int dyn = 122880;   // 120KB weight tiles in dynamic LDS
  static int attr_done = 0;
  if (!attr_done) {
    hipFuncSetAttribute(reinterpret_cast<const void*>(gru_pipeline<2,2>),
                        hipFuncAttributeMaxDynamicSharedMemorySize, dyn);
    hipFuncSetAttribute(reinterpret_cast<const void*>(gru_pipeline<2,1>),
                        hipFuncAttributeMaxDynamicSharedMemorySize, dyn);
    hipFuncSetAttribute(reinterpret_cast<const void*>(gru_pipeline<1,1>),
                        hipFuncAttributeMaxDynamicSharedMemorySize, dyn);
    attr_done = 1;
  }

  hipMemsetAsync(ws, 0, 65536, stream);     // zero flags every launch

#define LAUNCH(CE, CD)                                                     \
  gru_pipeline<CE, CD><<<256, 512, dyn, stream>>>(                         \
      d_in[0], d_in[1], d_in[2], d_in[3], d_in[4], d_in[5],                \
      d_in[6], d_in[7], d_in[8], d_in[9], d_in[10], d_in[11], d_in[12],    \
      d_out, pflag, cflag, ringE, ringD, RE, RW)

  if      (CHe == 2 && CHd == 2) LAUNCH(2, 2);
  else if (CHe == 2 && CHd == 1) LAUNCH(2, 1);
  else                           LAUNCH(1, 1);
#undef LAUNCH
  (void)in_sizes; (void)n_in;
}